// Round 2
// baseline (396.443 us; speedup 1.0000x reference)
//
#include <hip/hip_runtime.h>
#include <stdint.h>

#define NB 2
#define NN 2048
#define MM 64
#define CC 256
#define HH 8
#define DD 32
#define PP 6
#define ATT_SCALE 0.17677669529663687f  // 1/sqrt(32)

typedef __attribute__((ext_vector_type(8))) short short8;
typedef __attribute__((ext_vector_type(4))) float f32x4;

__device__ __forceinline__ uint16_t f2bf(float f) {
  union { float f; uint32_t u; } c; c.f = f;
  return (uint16_t)((c.u + 0x7fffu + ((c.u >> 16) & 1u)) >> 16);  // RNE
}

// ---------------------------------------------------------------------------
// Kernel 0: convert cf + the 4 weight matrices f32 -> bf16 (for MFMA GEMMs).
// Flat float4-index space: cf [0,262144), Wq, Wk, Wi, Wo (each 16384 float4s).
// ---------------------------------------------------------------------------
__global__ __launch_bounds__(256) void k_cvt(const float* __restrict__ cf,
                                             const float* __restrict__ Wq,
                                             const float* __restrict__ Wk,
                                             const float* __restrict__ Wi,
                                             const float* __restrict__ Wo,
                                             uint16_t* __restrict__ dst) {
  const int g = blockIdx.x * 256 + threadIdx.x;  // float4 index, < 327680
  const float* src; int off;
  if (g < 262144)      { src = cf; off = g; }
  else if (g < 278528) { src = Wq; off = g - 262144; }
  else if (g < 294912) { src = Wk; off = g - 278528; }
  else if (g < 311296) { src = Wi; off = g - 294912; }
  else                 { src = Wo; off = g - 311296; }
  const float4 v4 = *(const float4*)(src + (size_t)off * 4);
  ushort4 o;
  o.x = f2bf(v4.x); o.y = f2bf(v4.y); o.z = f2bf(v4.z); o.w = f2bf(v4.w);
  *(ushort4*)(dst + (size_t)g * 4) = o;
}

// ---------------------------------------------------------------------------
// Kernel 1: exact top-M (smallest distance) neighbor selection per (b,n).
// Distances bitwise-match numpy: sequential f32 mul/add (no FMA) + RN sqrt.
// Adaptive 256-bin histogram; boundary bin resolved exactly by (dist, index).
// Output order arbitrary — downstream is permutation-invariant over the set.
// ---------------------------------------------------------------------------
__global__ __launch_bounds__(256) void k_select(const float* __restrict__ pg,
                                                int* __restrict__ nidx) {
  const int row = blockIdx.x;   // b*N + n
  const int t = threadIdx.x;

  __shared__ float s_red[256];
  __shared__ float s_red2[256];
  __shared__ uint32_t s_hist[256];
  __shared__ uint32_t s_scan[256];
  __shared__ float s_cd[NN];
  __shared__ int   s_cj[NN];
  __shared__ int s_tbin;
  __shared__ uint32_t s_c0;
  __shared__ int s_cw;
  __shared__ int s_ct;

  // defensive default so any unwritten slot is finite & in-range
  if (t < MM) nidx[(size_t)row * MM + t] = t;

  const float2* base = (const float2*)(pg + (size_t)row * NN * PP);

  float d[8];
  float mn = 3.4e38f, mx = -3.4e38f;
#pragma unroll
  for (int i = 0; i < 8; i++) {
    const int j = t + i * 256;
    const float2 p0 = base[(size_t)j * 3 + 0];
    const float2 p1 = base[(size_t)j * 3 + 1];
    const float2 p2 = base[(size_t)j * 3 + 2];
    float s = __fmul_rn(p0.x, p0.x);
    s = __fadd_rn(s, __fmul_rn(p0.y, p0.y));
    s = __fadd_rn(s, __fmul_rn(p1.x, p1.x));
    s = __fadd_rn(s, __fmul_rn(p1.y, p1.y));
    s = __fadd_rn(s, __fmul_rn(p2.x, p2.x));
    s = __fadd_rn(s, __fmul_rn(p2.y, p2.y));
    const float dist = __fsqrt_rn(s);
    d[i] = dist;
    mn = fminf(mn, dist);
    mx = fmaxf(mx, dist);
  }

  s_red[t] = mn; s_red2[t] = mx;
  __syncthreads();
  for (int off = 128; off; off >>= 1) {
    if (t < off) {
      s_red[t] = fminf(s_red[t], s_red[t + off]);
      s_red2[t] = fmaxf(s_red2[t], s_red2[t + off]);
    }
    __syncthreads();
  }
  mn = s_red[0];
  mx = s_red2[0];
  const float range = mx - mn;
  const float scale = (range > 0.f) ? (256.0f / range) : 0.f;

  s_hist[t] = 0;
  __syncthreads();
  int bins[8];
#pragma unroll
  for (int i = 0; i < 8; i++) {
    int bn = (int)((d[i] - mn) * scale);
    bn = (bn > 255) ? 255 : (bn < 0 ? 0 : bn);
    bins[i] = bn;
    atomicAdd(&s_hist[bn], 1u);
  }
  __syncthreads();

  // inclusive prefix sum
  s_scan[t] = s_hist[t];
  __syncthreads();
  for (int off = 1; off < 256; off <<= 1) {
    const uint32_t add = (t >= off) ? s_scan[t - off] : 0u;
    __syncthreads();
    s_scan[t] += add;
    __syncthreads();
  }

  if (t == 0) { s_cw = 0; s_ct = 0; }
  if (s_scan[t] >= (uint32_t)MM && (t == 0 || s_scan[t - 1] < (uint32_t)MM)) {
    s_tbin = t;
    s_c0 = (t == 0) ? 0u : s_scan[t - 1];
  }
  __syncthreads();

  const int tbin = s_tbin;
  const int c0 = (int)s_c0;

#pragma unroll
  for (int i = 0; i < 8; i++) {
    const int j = t + i * 256;
    if (bins[i] < tbin) {
      const int pos = atomicAdd(&s_cw, 1);
      if (pos < MM) nidx[(size_t)row * MM + pos] = j;
    } else if (bins[i] == tbin) {
      const int pos = atomicAdd(&s_ct, 1);
      s_cd[pos] = d[i];
      s_cj[pos] = j;
    }
  }
  __syncthreads();

  // wave 0: exact (dist, index)-ordered selection of remaining r slots
  if (t < 64) {
    const int cnt = s_ct;
    const int r = MM - c0;
    for (int it = 0; it < r; ++it) {
      float bd = 3.4e38f; int bj = 0x7fffffff; int bi = -1;
      for (int i = t; i < cnt; i += 64) {
        const float dd = s_cd[i]; const int jj = s_cj[i];
        if (dd < bd || (dd == bd && jj < bj)) { bd = dd; bj = jj; bi = i; }
      }
#pragma unroll
      for (int off = 32; off; off >>= 1) {
        const float od = __shfl_xor(bd, off);
        const int oj = __shfl_xor(bj, off);
        const int oi = __shfl_xor(bi, off);
        if (od < bd || (od == bd && oj < bj)) { bd = od; bj = oj; bi = oi; }
      }
      if (t == 0 && bi >= 0) {
        s_cd[bi] = 3.4e38f;
        nidx[(size_t)row * MM + c0 + it] = bj;
      }
      __threadfence_block();
    }
  }
}

// ---------------------------------------------------------------------------
// MFMA bf16 GEMM-BT: O[r,c] = sum_k A[r,k] * W[c,k] + bias[c]
// A: (4096 x 256) bf16, W: (256 x 256) bf16, bias f32, O f32.
// 16x16x32 bf16 MFMA; A/B frag: row(or col)=lane&15, k=quad*8+j (16B load).
// C/D: col=lane&15, row=quad*4+reg (m89/m91-verified).
// ---------------------------------------------------------------------------
__device__ __forceinline__ void gemm_bt_body(const uint16_t* __restrict__ A,
                                             const uint16_t* __restrict__ W,
                                             const float* __restrict__ bias,
                                             float* __restrict__ O) {
  const int wave = threadIdx.x >> 6;
  const int lane = threadIdx.x & 63;
  const int m = lane & 15;
  const int quad = lane >> 4;
  const int row0 = blockIdx.x * 64 + wave * 16;
  const int c0 = blockIdx.y * 64;

  f32x4 acc0 = {0.f, 0.f, 0.f, 0.f};
  f32x4 acc1 = {0.f, 0.f, 0.f, 0.f};
  f32x4 acc2 = {0.f, 0.f, 0.f, 0.f};
  f32x4 acc3 = {0.f, 0.f, 0.f, 0.f};

#pragma unroll
  for (int k0 = 0; k0 < CC; k0 += 32) {
    const short8 a = *(const short8*)(A + (size_t)(row0 + m) * CC + k0 + quad * 8);
    const short8 b0 = *(const short8*)(W + (size_t)(c0 + 0 + m) * CC + k0 + quad * 8);
    const short8 b1 = *(const short8*)(W + (size_t)(c0 + 16 + m) * CC + k0 + quad * 8);
    const short8 b2 = *(const short8*)(W + (size_t)(c0 + 32 + m) * CC + k0 + quad * 8);
    const short8 b3 = *(const short8*)(W + (size_t)(c0 + 48 + m) * CC + k0 + quad * 8);
    acc0 = __builtin_amdgcn_mfma_f32_16x16x32_bf16(a, b0, acc0, 0, 0, 0);
    acc1 = __builtin_amdgcn_mfma_f32_16x16x32_bf16(a, b1, acc1, 0, 0, 0);
    acc2 = __builtin_amdgcn_mfma_f32_16x16x32_bf16(a, b2, acc2, 0, 0, 0);
    acc3 = __builtin_amdgcn_mfma_f32_16x16x32_bf16(a, b3, acc3, 0, 0, 0);
  }

  const int orow = row0 + quad * 4;
  f32x4 accs[4] = {acc0, acc1, acc2, acc3};
#pragma unroll
  for (int f = 0; f < 4; ++f) {
    const int col = c0 + f * 16 + m;
    const float bv = bias[col];
#pragma unroll
    for (int r = 0; r < 4; ++r) {
      O[(size_t)(orow + r) * CC + col] = accs[f][r] + bv;
    }
  }
}

__global__ __launch_bounds__(256) void k_gemm_qkv(
    const uint16_t* __restrict__ A,
    const uint16_t* __restrict__ W0, const uint16_t* __restrict__ W1, const uint16_t* __restrict__ W2,
    const float* __restrict__ b0, const float* __restrict__ b1, const float* __restrict__ b2,
    float* __restrict__ O0, float* __restrict__ O1, float* __restrict__ O2) {
  const uint16_t* W = (blockIdx.z == 0) ? W0 : ((blockIdx.z == 1) ? W1 : W2);
  const float* bias = (blockIdx.z == 0) ? b0 : ((blockIdx.z == 1) ? b1 : b2);
  float* O = (blockIdx.z == 0) ? O0 : ((blockIdx.z == 1) ? O1 : O2);
  gemm_bt_body(A, W, bias, O);
}

__global__ __launch_bounds__(256) void k_gemm_out(const uint16_t* __restrict__ A,
                                                  const uint16_t* __restrict__ W,
                                                  const float* __restrict__ bias,
                                                  float* __restrict__ O) {
  gemm_bt_body(A, W, bias, O);
}

// ---------------------------------------------------------------------------
// Kernel 3: fused attention per (b,n).
// score[m,h] = ((Q[h]+u[h])·K[idx_m,h] + Σ_p npg[m,p]·W~[h,p] + c~[h]) * SCALE
//   W~[h,p] = Σ_d Wl[h*32+d,p]·(Q+v)[h,d],  c~[h] = Σ_d bl[h*32+d]·(Q+v)[h,d]
// softmax over m, then attnV[c] = Σ_m P[m,h]·V[idx_m, c]   (c = h*32+d)
// ---------------------------------------------------------------------------
__global__ __launch_bounds__(256) void k_attn(const float* __restrict__ pg,
                                              const int* __restrict__ nidx,
                                              const float* __restrict__ Q,
                                              const float* __restrict__ K,
                                              const float* __restrict__ V,
                                              const float* __restrict__ Wl,
                                              const float* __restrict__ bl,
                                              const float* __restrict__ u,
                                              const float* __restrict__ v,
                                              uint16_t* __restrict__ attnV) {
  const int row = blockIdx.x;       // b*N + n
  const int b = row >> 11;          // N = 2048
  const int t = threadIdx.x;
  const int wave = t >> 6;
  const int lane = t & 63;

  __shared__ int s_idx[MM];
  __shared__ float s_npg[MM][7];    // stride 7: conflict-free (gcd(7,32)=1)
  __shared__ float s_qu[CC];
  __shared__ float s_wt[HH][8];     // [h][0..5]=W~, [h][6]=c~
  __shared__ float s_sc[HH][MM];    // scores -> probabilities

  if (t < MM) s_idx[t] = nidx[(size_t)row * MM + t] & (NN - 1);  // mask: defensive
  const float qv_ = Q[(size_t)row * CC + t];
  s_qu[t] = qv_ + u[t];
  __syncthreads();

  if (t < MM) {
    const int jj = s_idx[t];
    const float2* p = (const float2*)(pg + ((size_t)row * NN + (size_t)jj) * PP);
    const float2 p0 = p[0], p1 = p[1], p2 = p[2];
    s_npg[t][0] = p0.x; s_npg[t][1] = p0.y;
    s_npg[t][2] = p1.x; s_npg[t][3] = p1.y;
    s_npg[t][4] = p2.x; s_npg[t][5] = p2.y;
  }

  // W~ and c~: thread t = channel c = h*32+d; reduce over d within 32-lane halves
  {
    const int h = t >> 5;
    const float qpv = qv_ + v[t];
    float part[7];
#pragma unroll
    for (int p = 0; p < 6; p++) part[p] = Wl[(size_t)t * PP + p] * qpv;
    part[6] = bl[t] * qpv;
#pragma unroll
    for (int off = 1; off < 32; off <<= 1) {
#pragma unroll
      for (int p = 0; p < 7; p++) part[p] += __shfl_xor(part[p], off);
    }
    if ((t & 31) == 0) {
#pragma unroll
      for (int p = 0; p < 7; p++) s_wt[h][p] = part[p];
    }
  }
  __syncthreads();

  // scores: wave w handles h=w and h=w+4; m = lane
#pragma unroll
  for (int pr = 0; pr < 2; ++pr) {
    const int h = wave + pr * 4;
    const int m = lane;
    const int kidx = s_idx[m];
    const float* krow = K + ((size_t)(b * NN + kidx)) * CC + h * DD;
    float acc = s_wt[h][6];
#pragma unroll
    for (int p = 0; p < 6; p++) acc += s_npg[m][p] * s_wt[h][p];
    const float* qu = &s_qu[h * DD];
    float a2 = 0.f;
#pragma unroll
    for (int dd = 0; dd < DD; dd += 4) {
      const float4 kv = *(const float4*)(krow + dd);
      a2 += qu[dd] * kv.x + qu[dd + 1] * kv.y + qu[dd + 2] * kv.z + qu[dd + 3] * kv.w;
    }
    s_sc[h][m] = (acc + a2) * ATT_SCALE;
  }
  __syncthreads();

  // softmax over m (mask all-true)
#pragma unroll
  for (int pr = 0; pr < 2; ++pr) {
    const int h = wave + pr * 4;
    const float x = s_sc[h][lane];
    float mxv = x;
#pragma unroll
    for (int off = 32; off; off >>= 1) mxv = fmaxf(mxv, __shfl_xor(mxv, off));
    const float e = expf(x - mxv);
    float sm = e;
#pragma unroll
    for (int off = 32; off; off >>= 1) sm += __shfl_xor(sm, off);
    s_sc[h][lane] = e / sm;
  }
  __syncthreads();

  // weighted V sum: thread t = output channel c, h = c>>5
  {
    const int h = t >> 5;
    const float* Vb = V + (size_t)b * NN * CC;
    float acc = 0.f;
#pragma unroll 4
    for (int m = 0; m < MM; m++) {
      acc += s_sc[h][m] * Vb[(size_t)s_idx[m] * CC + t];
    }
    attnV[(size_t)row * CC + t] = f2bf(acc);
  }
}

// ---------------------------------------------------------------------------
extern "C" void kernel_launch(void* const* d_in, const int* in_sizes, int n_in,
                              void* d_out, int out_size, void* d_ws, size_t ws_size,
                              hipStream_t stream) {
  const float* pg = (const float*)d_in[0];   // pairwise_g   (B,N,N,POS) f32
  const float* cf = (const float*)d_in[1];   // coset_functions (B,N,C) f32
  // d_in[2] = mask (all true) — unused
  const float* Wq = (const float*)d_in[3];
  const float* bq = (const float*)d_in[4];
  const float* Wk = (const float*)d_in[5];
  const float* bk = (const float*)d_in[6];
  const float* Wl = (const float*)d_in[7];
  const float* bl = (const float*)d_in[8];
  const float* u  = (const float*)d_in[9];
  const float* v  = (const float*)d_in[10];
  const float* Wi = (const float*)d_in[11];
  const float* bi = (const float*)d_in[12];
  const float* Wo = (const float*)d_in[13];
  const float* bo = (const float*)d_in[14];

  char* ws = (char*)d_ws;
  int* nidx = (int*)ws;                                   // 1 MB
  float* Q  = (float*)(ws + (size_t)1 * (1 << 20));       // 4 MB
  float* K  = (float*)(ws + (size_t)5 * (1 << 20));       // 4 MB
  float* V  = (float*)(ws + (size_t)9 * (1 << 20));       // 4 MB
  uint16_t* aV = (uint16_t*)(ws + (size_t)13 * (1 << 20));    // 2 MB (bf16)
  uint16_t* cvtb = (uint16_t*)(ws + (size_t)15 * (1 << 20));  // 2.5 MB (bf16)
  uint16_t* cfb = cvtb;                  // 1,048,576 elems
  uint16_t* Wqb = cfb + 1048576;         // 65,536 elems each
  uint16_t* Wkb = Wqb + 65536;
  uint16_t* Wib = Wkb + 65536;
  uint16_t* Wob = Wib + 65536;
  float* out = (float*)d_out;

  hipLaunchKernelGGL(k_cvt, dim3(1280), dim3(256), 0, stream, cf, Wq, Wk, Wi, Wo, cvtb);
  hipLaunchKernelGGL(k_select, dim3(NB * NN), dim3(256), 0, stream, pg, nidx);
  hipLaunchKernelGGL(k_gemm_qkv, dim3(64, 4, 3), dim3(256), 0, stream,
                     cfb, Wqb, Wkb, Wib, bq, bk, bi, Q, K, V);
  hipLaunchKernelGGL(k_attn, dim3(NB * NN), dim3(256), 0, stream,
                     pg, nidx, Q, K, V, Wl, bl, u, v, aV);
  hipLaunchKernelGGL(k_gemm_out, dim3(64, 4), dim3(256), 0, stream,
                     aV, Wob, bo, out);
}

// Round 3
// 384.111 us; speedup vs baseline: 1.0321x; 1.0321x over previous
//
#include <hip/hip_runtime.h>
#include <stdint.h>

#define NB 2
#define NN 2048
#define MM 64
#define CC 256
#define HH 8
#define DD 32
#define PP 6
#define ATT_SCALE 0.17677669529663687f  // 1/sqrt(32)

typedef __attribute__((ext_vector_type(8))) short short8;
typedef __attribute__((ext_vector_type(4))) float f32x4;

__device__ __forceinline__ uint16_t f2bf(float f) {
  union { float f; uint32_t u; } c; c.f = f;
  return (uint16_t)((c.u + 0x7fffu + ((c.u >> 16) & 1u)) >> 16);  // RNE
}
__device__ __forceinline__ float blo(uint32_t u) {
  union { uint32_t u; float f; } c; c.u = u << 16; return c.f;
}
__device__ __forceinline__ float bhi(uint32_t u) {
  union { uint32_t u; float f; } c; c.u = u & 0xffff0000u; return c.f;
}
__device__ __forceinline__ short8 pack8(float4 a, float4 b) {
  short8 r;
  r[0] = (short)f2bf(a.x); r[1] = (short)f2bf(a.y);
  r[2] = (short)f2bf(a.z); r[3] = (short)f2bf(a.w);
  r[4] = (short)f2bf(b.x); r[5] = (short)f2bf(b.y);
  r[6] = (short)f2bf(b.z); r[7] = (short)f2bf(b.w);
  return r;
}

// ---------------------------------------------------------------------------
// Kernel 1: exact top-M neighbor selection per (b,n). f32 distances match
// numpy bitwise (sequential mul/add, RN sqrt). Adaptive 256-bin histogram;
// boundary bin resolved by (dist, index). Output set order arbitrary.
// float4 loads: thread handles 2 points (48 B) per iteration.
// ---------------------------------------------------------------------------
__global__ __launch_bounds__(256) void k_select(const float* __restrict__ pg,
                                                int* __restrict__ nidx) {
  const int row = blockIdx.x;   // b*N + n
  const int t = threadIdx.x;
  const int wave = t >> 6;
  const int lane = t & 63;

  __shared__ float s_mn[4], s_mx[4];
  __shared__ uint32_t s_hist[256];
  __shared__ uint32_t s_scan[256];
  __shared__ float s_cd[NN];
  __shared__ int   s_cj[NN];
  __shared__ int s_tbin;
  __shared__ uint32_t s_c0;
  __shared__ int s_cw;
  __shared__ int s_ct;

  // defensive default so any unwritten slot is finite & in-range
  if (t < MM) nidx[(size_t)row * MM + t] = t;

  const float4* base = (const float4*)(pg + (size_t)row * NN * PP);

  float d[8];
  float mn = 3.4e38f, mx = -3.4e38f;
#pragma unroll
  for (int i = 0; i < 4; i++) {
    const int j0 = i * 512 + 2 * t;             // thread covers points j0, j0+1
    const float4 qa = base[(size_t)(j0 >> 1) * 3 + 0];   // pt0: x y z w
    const float4 qb = base[(size_t)(j0 >> 1) * 3 + 1];   // pt0: 4 5 | pt1: 0 1
    const float4 qc = base[(size_t)(j0 >> 1) * 3 + 2];   // pt1: 2 3 4 5
    float s0 = __fmul_rn(qa.x, qa.x);
    s0 = __fadd_rn(s0, __fmul_rn(qa.y, qa.y));
    s0 = __fadd_rn(s0, __fmul_rn(qa.z, qa.z));
    s0 = __fadd_rn(s0, __fmul_rn(qa.w, qa.w));
    s0 = __fadd_rn(s0, __fmul_rn(qb.x, qb.x));
    s0 = __fadd_rn(s0, __fmul_rn(qb.y, qb.y));
    float s1 = __fmul_rn(qb.z, qb.z);
    s1 = __fadd_rn(s1, __fmul_rn(qb.w, qb.w));
    s1 = __fadd_rn(s1, __fmul_rn(qc.x, qc.x));
    s1 = __fadd_rn(s1, __fmul_rn(qc.y, qc.y));
    s1 = __fadd_rn(s1, __fmul_rn(qc.z, qc.z));
    s1 = __fadd_rn(s1, __fmul_rn(qc.w, qc.w));
    const float d0 = __fsqrt_rn(s0);
    const float d1 = __fsqrt_rn(s1);
    d[2 * i] = d0; d[2 * i + 1] = d1;
    mn = fminf(mn, fminf(d0, d1));
    mx = fmaxf(mx, fmaxf(d0, d1));
  }

  // wave shuffle min/max, then tiny LDS combine
#pragma unroll
  for (int off = 32; off; off >>= 1) {
    mn = fminf(mn, __shfl_xor(mn, off));
    mx = fmaxf(mx, __shfl_xor(mx, off));
  }
  if (lane == 0) { s_mn[wave] = mn; s_mx[wave] = mx; }
  s_hist[t] = 0;
  __syncthreads();
  mn = fminf(fminf(s_mn[0], s_mn[1]), fminf(s_mn[2], s_mn[3]));
  mx = fmaxf(fmaxf(s_mx[0], s_mx[1]), fmaxf(s_mx[2], s_mx[3]));
  const float range = mx - mn;
  const float scale = (range > 0.f) ? (256.0f / range) : 0.f;

  int bins[8];
#pragma unroll
  for (int i = 0; i < 8; i++) {
    int bn = (int)((d[i] - mn) * scale);
    bn = (bn > 255) ? 255 : (bn < 0 ? 0 : bn);
    bins[i] = bn;
    atomicAdd(&s_hist[bn], 1u);
  }
  __syncthreads();

  // inclusive prefix sum over 256 bins
  s_scan[t] = s_hist[t];
  __syncthreads();
  for (int off = 1; off < 256; off <<= 1) {
    const uint32_t add = (t >= off) ? s_scan[t - off] : 0u;
    __syncthreads();
    s_scan[t] += add;
    __syncthreads();
  }

  if (t == 0) { s_cw = 0; s_ct = 0; }
  if (s_scan[t] >= (uint32_t)MM && (t == 0 || s_scan[t - 1] < (uint32_t)MM)) {
    s_tbin = t;
    s_c0 = (t == 0) ? 0u : s_scan[t - 1];
  }
  __syncthreads();

  const int tbin = s_tbin;
  const int c0 = (int)s_c0;

#pragma unroll
  for (int i = 0; i < 8; i++) {
    const int j = (i >> 1) * 512 + 2 * t + (i & 1);
    if (bins[i] < tbin) {
      const int pos = atomicAdd(&s_cw, 1);
      if (pos < MM) nidx[(size_t)row * MM + pos] = j;
    } else if (bins[i] == tbin) {
      const int pos = atomicAdd(&s_ct, 1);
      s_cd[pos] = d[i];
      s_cj[pos] = j;
    }
  }
  __syncthreads();

  // wave 0: exact (dist, index)-ordered pick of remaining r slots
  if (t < 64) {
    const int cnt = s_ct;
    const int r = MM - c0;
    for (int it = 0; it < r; ++it) {
      float bd = 3.4e38f; int bj = 0x7fffffff; int bi = -1;
      for (int i = t; i < cnt; i += 64) {
        const float dd = s_cd[i]; const int jj = s_cj[i];
        if (dd < bd || (dd == bd && jj < bj)) { bd = dd; bj = jj; bi = i; }
      }
#pragma unroll
      for (int off = 32; off; off >>= 1) {
        const float od = __shfl_xor(bd, off);
        const int oj = __shfl_xor(bj, off);
        const int oi = __shfl_xor(bi, off);
        if (od < bd || (od == bd && oj < bj)) { bd = od; bj = oj; bi = oi; }
      }
      if (t == 0 && bi >= 0) {
        s_cd[bi] = 3.4e38f;
        nidx[(size_t)row * MM + c0 + it] = bj;
      }
      __threadfence_block();
    }
  }
}

// ---------------------------------------------------------------------------
// QKV GEMM: single-wave blocks (64 thr), 16 rows x 64 cols per wave.
// f32 inputs converted to bf16 in-register (no staging pass).
// O[r,c] = sum_k A[r,k]*W[c,k] + bias[c].  z=0 -> Q (f32); z=1 -> K (bf16);
// z=2 -> V (bf16). Frag: row/col=lane&15, k=quad*8+j. C/D: col=lane&15,
// row=quad*4+reg.
// ---------------------------------------------------------------------------
__global__ __launch_bounds__(64) void k_gemm_qkv(
    const float* __restrict__ A,
    const float* __restrict__ W0, const float* __restrict__ W1, const float* __restrict__ W2,
    const float* __restrict__ b0, const float* __restrict__ b1, const float* __restrict__ b2,
    float* __restrict__ Qo, uint16_t* __restrict__ Ko, uint16_t* __restrict__ Vo) {
  const int z = blockIdx.z;
  const float* W = (z == 0) ? W0 : ((z == 1) ? W1 : W2);
  const float* bias = (z == 0) ? b0 : ((z == 1) ? b1 : b2);

  const int lane = threadIdx.x;
  const int m = lane & 15;
  const int quad = lane >> 4;
  const int row0 = blockIdx.x * 16;
  const int c0 = blockIdx.y * 64;

  f32x4 acc0 = {0.f, 0.f, 0.f, 0.f};
  f32x4 acc1 = {0.f, 0.f, 0.f, 0.f};
  f32x4 acc2 = {0.f, 0.f, 0.f, 0.f};
  f32x4 acc3 = {0.f, 0.f, 0.f, 0.f};

#pragma unroll
  for (int k0 = 0; k0 < CC; k0 += 32) {
    const float4* ap = (const float4*)(A + (size_t)(row0 + m) * CC + k0 + quad * 8);
    const float4* bp0 = (const float4*)(W + (size_t)(c0 + 0 + m) * CC + k0 + quad * 8);
    const float4* bp1 = (const float4*)(W + (size_t)(c0 + 16 + m) * CC + k0 + quad * 8);
    const float4* bp2 = (const float4*)(W + (size_t)(c0 + 32 + m) * CC + k0 + quad * 8);
    const float4* bp3 = (const float4*)(W + (size_t)(c0 + 48 + m) * CC + k0 + quad * 8);
    const short8 a = pack8(ap[0], ap[1]);
    const short8 f0 = pack8(bp0[0], bp0[1]);
    const short8 f1 = pack8(bp1[0], bp1[1]);
    const short8 f2 = pack8(bp2[0], bp2[1]);
    const short8 f3 = pack8(bp3[0], bp3[1]);
    acc0 = __builtin_amdgcn_mfma_f32_16x16x32_bf16(a, f0, acc0, 0, 0, 0);
    acc1 = __builtin_amdgcn_mfma_f32_16x16x32_bf16(a, f1, acc1, 0, 0, 0);
    acc2 = __builtin_amdgcn_mfma_f32_16x16x32_bf16(a, f2, acc2, 0, 0, 0);
    acc3 = __builtin_amdgcn_mfma_f32_16x16x32_bf16(a, f3, acc3, 0, 0, 0);
  }

  const int orow = row0 + quad * 4;
  f32x4 accs[4] = {acc0, acc1, acc2, acc3};
#pragma unroll
  for (int f = 0; f < 4; ++f) {
    const int col = c0 + f * 16 + m;
    const float bv = bias[col];
#pragma unroll
    for (int r = 0; r < 4; ++r) {
      const float val = accs[f][r] + bv;
      const size_t o = (size_t)(orow + r) * CC + col;
      if (z == 0) Qo[o] = val;
      else if (z == 1) Ko[o] = f2bf(val);
      else Vo[o] = f2bf(val);
    }
  }
}

// ---------------------------------------------------------------------------
// Output GEMM: A = attnV (bf16), W = Wo (f32, converted in-register).
// Single-wave blocks, 16 rows x 32 cols per wave, grid (256, 8).
// ---------------------------------------------------------------------------
__global__ __launch_bounds__(64) void k_gemm_out(const uint16_t* __restrict__ A,
                                                 const float* __restrict__ W,
                                                 const float* __restrict__ bias,
                                                 float* __restrict__ O) {
  const int lane = threadIdx.x;
  const int m = lane & 15;
  const int quad = lane >> 4;
  const int row0 = blockIdx.x * 16;
  const int c0 = blockIdx.y * 32;

  f32x4 acc0 = {0.f, 0.f, 0.f, 0.f};
  f32x4 acc1 = {0.f, 0.f, 0.f, 0.f};

#pragma unroll
  for (int k0 = 0; k0 < CC; k0 += 32) {
    const short8 a = *(const short8*)(A + (size_t)(row0 + m) * CC + k0 + quad * 8);
    const float4* bp0 = (const float4*)(W + (size_t)(c0 + 0 + m) * CC + k0 + quad * 8);
    const float4* bp1 = (const float4*)(W + (size_t)(c0 + 16 + m) * CC + k0 + quad * 8);
    const short8 f0 = pack8(bp0[0], bp0[1]);
    const short8 f1 = pack8(bp1[0], bp1[1]);
    acc0 = __builtin_amdgcn_mfma_f32_16x16x32_bf16(a, f0, acc0, 0, 0, 0);
    acc1 = __builtin_amdgcn_mfma_f32_16x16x32_bf16(a, f1, acc1, 0, 0, 0);
  }

  const int orow = row0 + quad * 4;
  f32x4 accs[2] = {acc0, acc1};
#pragma unroll
  for (int f = 0; f < 2; ++f) {
    const int col = c0 + f * 16 + m;
    const float bv = bias[col];
#pragma unroll
    for (int r = 0; r < 4; ++r) {
      O[(size_t)(orow + r) * CC + col] = accs[f][r] + bv;
    }
  }
}

// ---------------------------------------------------------------------------
// Fused attention per (b,n). K, V are bf16 (halved gather traffic).
// score[m,h] = ((Q[h]+u[h])·K[idx_m,h] + Σ_p npg[m,p]·W~[h,p] + c~[h]) * SCALE
//   W~[h,p] = Σ_d Wl[h*32+d,p]·(Q+v)[h,d],  c~[h] = Σ_d bl[h*32+d]·(Q+v)[h,d]
// softmax over m; attnV[c] = Σ_m P[m,h]·V[idx_m,c]
// ---------------------------------------------------------------------------
__global__ __launch_bounds__(256) void k_attn(const float* __restrict__ pg,
                                              const int* __restrict__ nidx,
                                              const float* __restrict__ Q,
                                              const uint16_t* __restrict__ K,
                                              const uint16_t* __restrict__ V,
                                              const float* __restrict__ Wl,
                                              const float* __restrict__ bl,
                                              const float* __restrict__ u,
                                              const float* __restrict__ v,
                                              uint16_t* __restrict__ attnV) {
  const int row = blockIdx.x;       // b*N + n
  const int b = row >> 11;          // N = 2048
  const int t = threadIdx.x;
  const int wave = t >> 6;
  const int lane = t & 63;

  __shared__ int s_idx[MM];
  __shared__ float s_npg[MM][7];    // stride 7: conflict-free
  __shared__ float s_qu[CC];
  __shared__ float s_wt[HH][8];     // [h][0..5]=W~, [h][6]=c~
  __shared__ float s_sc[HH][MM];    // scores -> probabilities
  __shared__ float s_part[CC];      // cross-half V partials

  if (t < MM) s_idx[t] = nidx[(size_t)row * MM + t] & (NN - 1);
  const float qv_ = Q[(size_t)row * CC + t];
  s_qu[t] = qv_ + u[t];
  __syncthreads();

  if (t < MM) {
    const int jj = s_idx[t];
    const float2* p = (const float2*)(pg + ((size_t)row * NN + (size_t)jj) * PP);
    const float2 p0 = p[0], p1 = p[1], p2 = p[2];
    s_npg[t][0] = p0.x; s_npg[t][1] = p0.y;
    s_npg[t][2] = p1.x; s_npg[t][3] = p1.y;
    s_npg[t][4] = p2.x; s_npg[t][5] = p2.y;
  }

  // W~ and c~: thread t = channel c = h*32+d; reduce within 32-lane halves
  {
    const int h = t >> 5;
    const float qpv = qv_ + v[t];
    float part[7];
#pragma unroll
    for (int p = 0; p < 6; p++) part[p] = Wl[(size_t)t * PP + p] * qpv;
    part[6] = bl[t] * qpv;
#pragma unroll
    for (int off = 1; off < 32; off <<= 1) {
#pragma unroll
      for (int p = 0; p < 7; p++) part[p] += __shfl_xor(part[p], off);
    }
    if ((t & 31) == 0) {
#pragma unroll
      for (int p = 0; p < 7; p++) s_wt[h][p] = part[p];
    }
  }
  __syncthreads();

  // scores: wave w handles h=w and h=w+4; m = lane. K is bf16.
#pragma unroll
  for (int pr = 0; pr < 2; ++pr) {
    const int h = wave + pr * 4;
    const int m = lane;
    const int kidx = s_idx[m];
    const uint4* kr = (const uint4*)(K + ((size_t)(b * NN + kidx)) * CC + h * DD);
    float acc = s_wt[h][6];
#pragma unroll
    for (int p = 0; p < 6; p++) acc += s_npg[m][p] * s_wt[h][p];
    const float* qu = &s_qu[h * DD];
    float a2 = 0.f;
#pragma unroll
    for (int w4 = 0; w4 < 4; w4++) {
      const uint4 kv = kr[w4];
      const float* q8 = qu + w4 * 8;
      a2 += q8[0] * blo(kv.x) + q8[1] * bhi(kv.x)
          + q8[2] * blo(kv.y) + q8[3] * bhi(kv.y)
          + q8[4] * blo(kv.z) + q8[5] * bhi(kv.z)
          + q8[6] * blo(kv.w) + q8[7] * bhi(kv.w);
    }
    s_sc[h][m] = (acc + a2) * ATT_SCALE;
  }
  __syncthreads();

  // softmax over m
#pragma unroll
  for (int pr = 0; pr < 2; ++pr) {
    const int h = wave + pr * 4;
    const float x = s_sc[h][lane];
    float mxv = x;
#pragma unroll
    for (int off = 32; off; off >>= 1) mxv = fmaxf(mxv, __shfl_xor(mxv, off));
    const float e = expf(x - mxv);
    float sm = e;
#pragma unroll
    for (int off = 32; off; off >>= 1) sm += __shfl_xor(sm, off);
    s_sc[h][lane] = e / sm;
  }
  __syncthreads();

  // weighted V sum (bf16 V, uint32 = 2 channels/lane, 2 m-halves)
  {
    const int h2 = t >> 7;          // which m-parity this half handles
    const int ci = (t & 127) * 2;   // even channel base
    const int h = ci >> 5;
    const uint32_t* Vb32 = (const uint32_t*)(V + (size_t)b * NN * CC);
    float a0 = 0.f, a1 = 0.f;
#pragma unroll 8
    for (int m = h2; m < MM; m += 2) {
      const uint32_t pv = Vb32[(size_t)s_idx[m] * (CC / 2) + (ci >> 1)];
      const float p = s_sc[h][m];
      a0 += p * blo(pv);
      a1 += p * bhi(pv);
    }
    if (h2 == 1) { s_part[ci] = a0; s_part[ci + 1] = a1; }
    __syncthreads();
    if (h2 == 0) {
      attnV[(size_t)row * CC + ci]     = f2bf(a0 + s_part[ci]);
      attnV[(size_t)row * CC + ci + 1] = f2bf(a1 + s_part[ci + 1]);
    }
  }
}

// ---------------------------------------------------------------------------
extern "C" void kernel_launch(void* const* d_in, const int* in_sizes, int n_in,
                              void* d_out, int out_size, void* d_ws, size_t ws_size,
                              hipStream_t stream) {
  const float* pg = (const float*)d_in[0];
  const float* cf = (const float*)d_in[1];
  // d_in[2] = mask (all true) — unused
  const float* Wq = (const float*)d_in[3];
  const float* bq = (const float*)d_in[4];
  const float* Wk = (const float*)d_in[5];
  const float* bk = (const float*)d_in[6];
  const float* Wl = (const float*)d_in[7];
  const float* bl = (const float*)d_in[8];
  const float* u  = (const float*)d_in[9];
  const float* v  = (const float*)d_in[10];
  const float* Wi = (const float*)d_in[11];
  const float* bi = (const float*)d_in[12];
  const float* Wo = (const float*)d_in[13];
  const float* bo = (const float*)d_in[14];

  char* ws = (char*)d_ws;
  int* nidx = (int*)ws;                                    // 1 MB
  float* Q  = (float*)(ws + (size_t)1 * (1 << 20));        // 4 MB (f32)
  uint16_t* K = (uint16_t*)(ws + (size_t)5 * (1 << 20));   // 2 MB (bf16)
  uint16_t* V = (uint16_t*)(ws + (size_t)7 * (1 << 20));   // 2 MB (bf16)
  uint16_t* aV = (uint16_t*)(ws + (size_t)9 * (1 << 20));  // 2 MB (bf16)
  float* out = (float*)d_out;

  hipLaunchKernelGGL(k_gemm_qkv, dim3(256, 4, 3), dim3(64), 0, stream,
                     cf, Wq, Wk, Wi, bq, bk, bi, Q, K, V);
  hipLaunchKernelGGL(k_select, dim3(NB * NN), dim3(256), 0, stream, pg, nidx);
  hipLaunchKernelGGL(k_attn, dim3(NB * NN), dim3(256), 0, stream,
                     pg, nidx, Q, K, V, Wl, bl, u, v, aV);
  hipLaunchKernelGGL(k_gemm_out, dim3(256, 8), dim3(64), 0, stream,
                     aV, Wo, bo, out);
}

// Round 4
// 358.989 us; speedup vs baseline: 1.1043x; 1.0700x over previous
//
#include <hip/hip_runtime.h>
#include <stdint.h>

#define NB 2
#define NN 2048
#define MM 64
#define CC 256
#define HH 8
#define DD 32
#define PP 6
#define ATT_SCALE 0.17677669529663687f  // 1/sqrt(32)

typedef __attribute__((ext_vector_type(8))) short short8;
typedef __attribute__((ext_vector_type(4))) float f32x4;

__device__ __forceinline__ uint16_t f2bf(float f) {
  union { float f; uint32_t u; } c; c.f = f;
  return (uint16_t)((c.u + 0x7fffu + ((c.u >> 16) & 1u)) >> 16);  // RNE
}
__device__ __forceinline__ float blo(uint32_t u) {
  union { uint32_t u; float f; } c; c.u = u << 16; return c.f;
}
__device__ __forceinline__ float bhi(uint32_t u) {
  union { uint32_t u; float f; } c; c.u = u & 0xffff0000u; return c.f;
}
__device__ __forceinline__ short8 pack8(float4 a, float4 b) {
  short8 r;
  r[0] = (short)f2bf(a.x); r[1] = (short)f2bf(a.y);
  r[2] = (short)f2bf(a.z); r[3] = (short)f2bf(a.w);
  r[4] = (short)f2bf(b.x); r[5] = (short)f2bf(b.y);
  r[6] = (short)f2bf(b.z); r[7] = (short)f2bf(b.w);
  return r;
}

// ---------------------------------------------------------------------------
// QKV GEMM: single-wave blocks (64 thr), 16 rows x 64 cols per wave.
// f32 inputs converted to bf16 in-register. z=0 -> Q (f32); z=1 -> K (bf16);
// z=2 -> V (bf16). Frag: row/col=lane&15, k=quad*8+j. C/D: col=lane&15,
// row=quad*4+reg.
// ---------------------------------------------------------------------------
__global__ __launch_bounds__(64) void k_gemm_qkv(
    const float* __restrict__ A,
    const float* __restrict__ W0, const float* __restrict__ W1, const float* __restrict__ W2,
    const float* __restrict__ b0, const float* __restrict__ b1, const float* __restrict__ b2,
    float* __restrict__ Qo, uint16_t* __restrict__ Ko, uint16_t* __restrict__ Vo) {
  const int z = blockIdx.z;
  const float* W = (z == 0) ? W0 : ((z == 1) ? W1 : W2);
  const float* bias = (z == 0) ? b0 : ((z == 1) ? b1 : b2);

  const int lane = threadIdx.x;
  const int m = lane & 15;
  const int quad = lane >> 4;
  const int row0 = blockIdx.x * 16;
  const int c0 = blockIdx.y * 64;

  f32x4 acc0 = {0.f, 0.f, 0.f, 0.f};
  f32x4 acc1 = {0.f, 0.f, 0.f, 0.f};
  f32x4 acc2 = {0.f, 0.f, 0.f, 0.f};
  f32x4 acc3 = {0.f, 0.f, 0.f, 0.f};

#pragma unroll
  for (int k0 = 0; k0 < CC; k0 += 32) {
    const float4* ap = (const float4*)(A + (size_t)(row0 + m) * CC + k0 + quad * 8);
    const float4* bp0 = (const float4*)(W + (size_t)(c0 + 0 + m) * CC + k0 + quad * 8);
    const float4* bp1 = (const float4*)(W + (size_t)(c0 + 16 + m) * CC + k0 + quad * 8);
    const float4* bp2 = (const float4*)(W + (size_t)(c0 + 32 + m) * CC + k0 + quad * 8);
    const float4* bp3 = (const float4*)(W + (size_t)(c0 + 48 + m) * CC + k0 + quad * 8);
    const short8 a = pack8(ap[0], ap[1]);
    const short8 f0 = pack8(bp0[0], bp0[1]);
    const short8 f1 = pack8(bp1[0], bp1[1]);
    const short8 f2 = pack8(bp2[0], bp2[1]);
    const short8 f3 = pack8(bp3[0], bp3[1]);
    acc0 = __builtin_amdgcn_mfma_f32_16x16x32_bf16(a, f0, acc0, 0, 0, 0);
    acc1 = __builtin_amdgcn_mfma_f32_16x16x32_bf16(a, f1, acc1, 0, 0, 0);
    acc2 = __builtin_amdgcn_mfma_f32_16x16x32_bf16(a, f2, acc2, 0, 0, 0);
    acc3 = __builtin_amdgcn_mfma_f32_16x16x32_bf16(a, f3, acc3, 0, 0, 0);
  }

  const int orow = row0 + quad * 4;
  f32x4 accs[4] = {acc0, acc1, acc2, acc3};
#pragma unroll
  for (int f = 0; f < 4; ++f) {
    const int col = c0 + f * 16 + m;
    const float bv = bias[col];
#pragma unroll
    for (int r = 0; r < 4; ++r) {
      const float val = accs[f][r] + bv;
      const size_t o = (size_t)(orow + r) * CC + col;
      if (z == 0) Qo[o] = val;
      else if (z == 1) Ko[o] = f2bf(val);
      else Vo[o] = f2bf(val);
    }
  }
}

// ---------------------------------------------------------------------------
// Output GEMM: A = attnV (bf16), W = Wo (f32 -> bf16 in-register).
// ---------------------------------------------------------------------------
__global__ __launch_bounds__(64) void k_gemm_out(const uint16_t* __restrict__ A,
                                                 const float* __restrict__ W,
                                                 const float* __restrict__ bias,
                                                 float* __restrict__ O) {
  const int lane = threadIdx.x;
  const int m = lane & 15;
  const int quad = lane >> 4;
  const int row0 = blockIdx.x * 16;
  const int c0 = blockIdx.y * 32;

  f32x4 acc0 = {0.f, 0.f, 0.f, 0.f};
  f32x4 acc1 = {0.f, 0.f, 0.f, 0.f};

#pragma unroll
  for (int k0 = 0; k0 < CC; k0 += 32) {
    const short8 a = *(const short8*)(A + (size_t)(row0 + m) * CC + k0 + quad * 8);
    const float4* bp0 = (const float4*)(W + (size_t)(c0 + 0 + m) * CC + k0 + quad * 8);
    const float4* bp1 = (const float4*)(W + (size_t)(c0 + 16 + m) * CC + k0 + quad * 8);
    const short8 f0 = pack8(bp0[0], bp0[1]);
    const short8 f1 = pack8(bp1[0], bp1[1]);
    acc0 = __builtin_amdgcn_mfma_f32_16x16x32_bf16(a, f0, acc0, 0, 0, 0);
    acc1 = __builtin_amdgcn_mfma_f32_16x16x32_bf16(a, f1, acc1, 0, 0, 0);
  }

  const int orow = row0 + quad * 4;
  f32x4 accs[2] = {acc0, acc1};
#pragma unroll
  for (int f = 0; f < 2; ++f) {
    const int col = c0 + f * 16 + m;
    const float bv = bias[col];
#pragma unroll
    for (int r = 0; r < 4; ++r) {
      O[(size_t)(orow + r) * CC + col] = accs[f][r] + bv;
    }
  }
}

// ---------------------------------------------------------------------------
// FUSED select + attention per (b,n).
// Phase B: exact top-M (numpy-bitwise distances, adaptive histogram; boundary
//   bin resolved by (dist, index)) -> s_idx in LDS. Wave-shuffle scan (2
//   barriers instead of 16).
// Phase C: gather pg comps for the 64 selected (L2-hot: the row was just
//   streamed), folded e-term, gathered QK scores, wave softmax, gathered V sum.
// ---------------------------------------------------------------------------
__global__ __launch_bounds__(256) void k_fused(const float* __restrict__ pg,
                                               const float* __restrict__ Q,
                                               const uint16_t* __restrict__ K,
                                               const uint16_t* __restrict__ V,
                                               const float* __restrict__ Wl,
                                               const float* __restrict__ bl,
                                               const float* __restrict__ u,
                                               const float* __restrict__ v,
                                               uint16_t* __restrict__ attnV) {
  const int row = blockIdx.x;   // b*N + n
  const int b = row >> 11;
  const int t = threadIdx.x;
  const int wave = t >> 6;
  const int lane = t & 63;

  __shared__ float s_mn[4], s_mx[4];
  __shared__ uint32_t s_wsum[4];
  __shared__ uint32_t s_hist[256];
  __shared__ uint32_t s_scan[256];
  __shared__ float s_cd[NN];
  __shared__ int   s_cj[NN];
  __shared__ int s_tbin;
  __shared__ uint32_t s_c0;
  __shared__ int s_cw;
  __shared__ int s_ct;
  __shared__ int s_idx[MM];
  __shared__ float s_npg[MM][7];
  __shared__ float s_qu[CC];
  __shared__ float s_wt[HH][8];
  __shared__ float s_sc[HH][MM];
  __shared__ float s_part[CC];

  // ---- Phase A: Q row + additive biases (issued early; used after barriers)
  const float qv_ = Q[(size_t)row * CC + t];
  s_qu[t] = qv_ + u[t];
  if (t < MM) s_idx[t] = t;   // defensive default

  // ---- Phase B: distances (bitwise-numpy), histogram top-M
  const float4* base = (const float4*)(pg + (size_t)row * NN * PP);

  float d[8];
  float mn = 3.4e38f, mx = -3.4e38f;
#pragma unroll
  for (int i = 0; i < 4; i++) {
    const int j0 = i * 512 + 2 * t;             // thread covers points j0, j0+1
    const float4 qa = base[(size_t)(j0 >> 1) * 3 + 0];
    const float4 qb = base[(size_t)(j0 >> 1) * 3 + 1];
    const float4 qc = base[(size_t)(j0 >> 1) * 3 + 2];
    float s0 = __fmul_rn(qa.x, qa.x);
    s0 = __fadd_rn(s0, __fmul_rn(qa.y, qa.y));
    s0 = __fadd_rn(s0, __fmul_rn(qa.z, qa.z));
    s0 = __fadd_rn(s0, __fmul_rn(qa.w, qa.w));
    s0 = __fadd_rn(s0, __fmul_rn(qb.x, qb.x));
    s0 = __fadd_rn(s0, __fmul_rn(qb.y, qb.y));
    float s1 = __fmul_rn(qb.z, qb.z);
    s1 = __fadd_rn(s1, __fmul_rn(qb.w, qb.w));
    s1 = __fadd_rn(s1, __fmul_rn(qc.x, qc.x));
    s1 = __fadd_rn(s1, __fmul_rn(qc.y, qc.y));
    s1 = __fadd_rn(s1, __fmul_rn(qc.z, qc.z));
    s1 = __fadd_rn(s1, __fmul_rn(qc.w, qc.w));
    const float d0 = __fsqrt_rn(s0);
    const float d1 = __fsqrt_rn(s1);
    d[2 * i] = d0; d[2 * i + 1] = d1;
    mn = fminf(mn, fminf(d0, d1));
    mx = fmaxf(mx, fmaxf(d0, d1));
  }

#pragma unroll
  for (int off = 32; off; off >>= 1) {
    mn = fminf(mn, __shfl_xor(mn, off));
    mx = fmaxf(mx, __shfl_xor(mx, off));
  }
  if (lane == 0) { s_mn[wave] = mn; s_mx[wave] = mx; }
  s_hist[t] = 0;
  __syncthreads();
  mn = fminf(fminf(s_mn[0], s_mn[1]), fminf(s_mn[2], s_mn[3]));
  mx = fmaxf(fmaxf(s_mx[0], s_mx[1]), fmaxf(s_mx[2], s_mx[3]));
  const float range = mx - mn;
  const float scale = (range > 0.f) ? (256.0f / range) : 0.f;

  int bins[8];
#pragma unroll
  for (int i = 0; i < 8; i++) {
    int bn = (int)((d[i] - mn) * scale);
    bn = (bn > 255) ? 255 : (bn < 0 ? 0 : bn);
    bins[i] = bn;
    atomicAdd(&s_hist[bn], 1u);
  }
  __syncthreads();

  // inclusive scan of 256 bins: wave shuffle scan + cross-wave combine
  {
    uint32_t x = s_hist[t];
#pragma unroll
    for (int off = 1; off < 64; off <<= 1) {
      const uint32_t y = __shfl_up(x, off);
      if (lane >= off) x += y;
    }
    if (lane == 63) s_wsum[wave] = x;
    __syncthreads();
    uint32_t pre = 0;
    for (int w = 0; w < wave; w++) pre += s_wsum[w];
    x += pre;
    s_scan[t] = x;
  }
  if (t == 0) { s_cw = 0; s_ct = 0; }
  __syncthreads();

  if (s_scan[t] >= (uint32_t)MM && (t == 0 || s_scan[t - 1] < (uint32_t)MM)) {
    s_tbin = t;
    s_c0 = (t == 0) ? 0u : s_scan[t - 1];
  }
  __syncthreads();

  const int tbin = s_tbin;
  const int c0 = (int)s_c0;

#pragma unroll
  for (int i = 0; i < 8; i++) {
    const int j = (i >> 1) * 512 + 2 * t + (i & 1);
    if (bins[i] < tbin) {
      const int pos = atomicAdd(&s_cw, 1);
      if (pos < MM) s_idx[pos] = j;
    } else if (bins[i] == tbin) {
      const int pos = atomicAdd(&s_ct, 1);
      s_cd[pos] = d[i];
      s_cj[pos] = j;
    }
  }
  __syncthreads();

  // wave 0: exact (dist, index)-ordered pick of remaining r slots
  if (t < 64) {
    const int cnt = s_ct;
    const int r = MM - c0;
    for (int it = 0; it < r; ++it) {
      float bd = 3.4e38f; int bj = 0x7fffffff; int bi = -1;
      for (int i = t; i < cnt; i += 64) {
        const float dd = s_cd[i]; const int jj = s_cj[i];
        if (dd < bd || (dd == bd && jj < bj)) { bd = dd; bj = jj; bi = i; }
      }
#pragma unroll
      for (int off = 32; off; off >>= 1) {
        const float od = __shfl_xor(bd, off);
        const int oj = __shfl_xor(bj, off);
        const int oi = __shfl_xor(bi, off);
        if (od < bd || (od == bd && oj < bj)) { bd = od; bj = oj; bi = oi; }
      }
      if (t == 0 && bi >= 0) {
        s_cd[bi] = 3.4e38f;
        s_idx[c0 + it] = bj;
      }
      __threadfence_block();
    }
  }
  __syncthreads();

  // ---- Phase C: gather pg comps for selected (L2-hot), W~/c~, scores
  if (t < MM) {
    const int jj = s_idx[t] & (NN - 1);
    const float2* p = (const float2*)(pg + ((size_t)row * NN + (size_t)jj) * PP);
    const float2 p0 = p[0], p1 = p[1], p2 = p[2];
    s_npg[t][0] = p0.x; s_npg[t][1] = p0.y;
    s_npg[t][2] = p1.x; s_npg[t][3] = p1.y;
    s_npg[t][4] = p2.x; s_npg[t][5] = p2.y;
  }

  {
    const int h = t >> 5;
    const float qpv = qv_ + v[t];
    float part[7];
#pragma unroll
    for (int p = 0; p < 6; p++) part[p] = Wl[(size_t)t * PP + p] * qpv;
    part[6] = bl[t] * qpv;
#pragma unroll
    for (int off = 1; off < 32; off <<= 1) {
#pragma unroll
      for (int p = 0; p < 7; p++) part[p] += __shfl_xor(part[p], off);
    }
    if ((t & 31) == 0) {
#pragma unroll
      for (int p = 0; p < 7; p++) s_wt[h][p] = part[p];
    }
  }
  __syncthreads();

  // scores: wave w handles h=w and h=w+4; m = lane. K is bf16.
#pragma unroll
  for (int pr = 0; pr < 2; ++pr) {
    const int h = wave + pr * 4;
    const int m = lane;
    const int kidx = s_idx[m] & (NN - 1);
    const uint4* kr = (const uint4*)(K + ((size_t)(b * NN + kidx)) * CC + h * DD);
    float acc = s_wt[h][6];
#pragma unroll
    for (int p = 0; p < 6; p++) acc += s_npg[m][p] * s_wt[h][p];
    const float* qu = &s_qu[h * DD];
    float a2 = 0.f;
#pragma unroll
    for (int w4 = 0; w4 < 4; w4++) {
      const uint4 kv = kr[w4];
      const float* q8 = qu + w4 * 8;
      a2 += q8[0] * blo(kv.x) + q8[1] * bhi(kv.x)
          + q8[2] * blo(kv.y) + q8[3] * bhi(kv.y)
          + q8[4] * blo(kv.z) + q8[5] * bhi(kv.z)
          + q8[6] * blo(kv.w) + q8[7] * bhi(kv.w);
    }
    s_sc[h][m] = (acc + a2) * ATT_SCALE;
  }
  __syncthreads();

  // softmax over m
#pragma unroll
  for (int pr = 0; pr < 2; ++pr) {
    const int h = wave + pr * 4;
    const float x = s_sc[h][lane];
    float mxv = x;
#pragma unroll
    for (int off = 32; off; off >>= 1) mxv = fmaxf(mxv, __shfl_xor(mxv, off));
    const float e = expf(x - mxv);
    float sm = e;
#pragma unroll
    for (int off = 32; off; off >>= 1) sm += __shfl_xor(sm, off);
    s_sc[h][lane] = e / sm;
  }
  __syncthreads();

  // weighted V sum (bf16 V, uint32 = 2 channels/lane, 2 m-halves)
  {
    const int h2 = t >> 7;
    const int ci = (t & 127) * 2;
    const int h = ci >> 5;
    const uint32_t* Vb32 = (const uint32_t*)(V + (size_t)b * NN * CC);
    float a0 = 0.f, a1 = 0.f;
#pragma unroll 8
    for (int m = h2; m < MM; m += 2) {
      const uint32_t pv = Vb32[(size_t)(s_idx[m] & (NN - 1)) * (CC / 2) + (ci >> 1)];
      const float p = s_sc[h][m];
      a0 += p * blo(pv);
      a1 += p * bhi(pv);
    }
    if (h2 == 1) { s_part[ci] = a0; s_part[ci + 1] = a1; }
    __syncthreads();
    if (h2 == 0) {
      attnV[(size_t)row * CC + ci]     = f2bf(a0 + s_part[ci]);
      attnV[(size_t)row * CC + ci + 1] = f2bf(a1 + s_part[ci + 1]);
    }
  }
}

// ---------------------------------------------------------------------------
extern "C" void kernel_launch(void* const* d_in, const int* in_sizes, int n_in,
                              void* d_out, int out_size, void* d_ws, size_t ws_size,
                              hipStream_t stream) {
  const float* pg = (const float*)d_in[0];
  const float* cf = (const float*)d_in[1];
  // d_in[2] = mask (all true) — unused
  const float* Wq = (const float*)d_in[3];
  const float* bq = (const float*)d_in[4];
  const float* Wk = (const float*)d_in[5];
  const float* bk = (const float*)d_in[6];
  const float* Wl = (const float*)d_in[7];
  const float* bl = (const float*)d_in[8];
  const float* u  = (const float*)d_in[9];
  const float* v  = (const float*)d_in[10];
  const float* Wi = (const float*)d_in[11];
  const float* bi = (const float*)d_in[12];
  const float* Wo = (const float*)d_in[13];
  const float* bo = (const float*)d_in[14];

  char* ws = (char*)d_ws;
  float* Q  = (float*)ws;                                  // 4 MB (f32)
  uint16_t* K = (uint16_t*)(ws + (size_t)4 * (1 << 20));   // 2 MB (bf16)
  uint16_t* V = (uint16_t*)(ws + (size_t)6 * (1 << 20));   // 2 MB (bf16)
  uint16_t* aV = (uint16_t*)(ws + (size_t)8 * (1 << 20));  // 2 MB (bf16)
  float* out = (float*)d_out;

  hipLaunchKernelGGL(k_gemm_qkv, dim3(256, 4, 3), dim3(64), 0, stream,
                     cf, Wq, Wk, Wi, bq, bk, bi, Q, K, V);
  hipLaunchKernelGGL(k_fused, dim3(NB * NN), dim3(256), 0, stream,
                     pg, Q, K, V, Wl, bl, u, v, aV);
  hipLaunchKernelGGL(k_gemm_out, dim3(256, 8), dim3(64), 0, stream,
                     aV, Wo, bo, out);
}